// Round 2
// baseline (12583.586 us; speedup 1.0000x reference)
//
#include <hip/hip_runtime.h>
#include <hip/hip_bf16.h>

#define T_STEPS 512
#define BATCH   256
#define DIM     256
#define HID     256
#define RG      16    // batch rows per workgroup
#define NG      16    // workgroups

using bf16x8  = __attribute__((ext_vector_type(8))) __bf16;
using bf16x4  = __attribute__((ext_vector_type(4))) __bf16;
using floatx4 = __attribute__((ext_vector_type(4))) float;

__device__ __forceinline__ float sigf(float x)   { return 1.0f / (1.0f + __expf(-x)); }
__device__ __forceinline__ float tanh_f(float x) { return 1.0f - 2.0f / (1.0f + __expf(2.0f * x)); }

__device__ __forceinline__ bf16x8 cvt8(const float* p) {
  floatx4 a = *(const floatx4*)p;
  floatx4 b = *(const floatx4*)(p + 4);
  bf16x8 r;
  r[0]=(__bf16)a[0]; r[1]=(__bf16)a[1]; r[2]=(__bf16)a[2]; r[3]=(__bf16)a[3];
  r[4]=(__bf16)b[0]; r[5]=(__bf16)b[1]; r[6]=(__bf16)b[2]; r[7]=(__bf16)b[3];
  return r;
}

// One WG owns RG=16 batch rows for the entire sequence. All 1024 gate-cols
// computed in-WG: weights live in registers (bf16, 256 VGPR/lane), h lives in
// LDS, cell state in registers. Zero inter-WG communication.
__global__ __launch_bounds__(1024, 1) void lstm_wg(
    const float* __restrict__ x, const float* __restrict__ h0,
    const float* __restrict__ c0,
    const float* __restrict__ mask_x, const float* __restrict__ mask_h,
    const float* __restrict__ W_ih, const float* __restrict__ W_hh,
    const float* __restrict__ b_ih, const float* __restrict__ b_hh,
    const int* __restrict__ bs_g,
    float* __restrict__ out, float* __restrict__ hn_out, float* __restrict__ cn_out) {

  const int tid  = threadIdx.x;
  const int r    = tid >> 6;            // wave id == hcol range [16r, 16r+16)
  const int lane = tid & 63;
  const int l15  = lane & 15;
  const int l4   = lane >> 4;           // 0..3
  const int row_base = blockIdx.x * RG;

  const int col = (r << 4) + l15;       // this lane's H-column (cell + B-frag col)
  const int rb4 = l4 * 4;               // first of 4 local rows this lane owns (C layout)

  __shared__ alignas(16) __bf16 s_x[RG * DIM];   // 8 KB, XOR-swizzled
  __shared__ alignas(16) __bf16 s_h[RG * HID];   // 8 KB, XOR-swizzled
  __shared__ int s_bs[T_STEPS];

  for (int i = tid; i < T_STEPS; i += 1024) s_bs[i] = bs_g[i];

  // ---- stationary weights -> registers (B-frag of mfma_f32_16x16x32_bf16) ----
  // B[k][n]: n = lane&15 (gate col), k = m*32 + 8*(lane>>4) + e
  bf16x8 wih[4][8], whh[4][8];
  #pragma unroll
  for (int q = 0; q < 4; ++q) {
    const size_t gc = (size_t)(q * HID + col) * DIM;
    #pragma unroll
    for (int m = 0; m < 8; ++m) {
      const int kb = m * 32 + l4 * 8;
      wih[q][m] = cvt8(W_ih + gc + kb);
      whh[q][m] = cvt8(W_hh + gc + kb);
    }
  }

  // bias per gate at this lane's column
  const float b_i = b_ih[0*HID + col] + b_hh[0*HID + col];
  const float b_f = b_ih[1*HID + col] + b_hh[1*HID + col];
  const float b_g = b_ih[2*HID + col] + b_hh[2*HID + col];
  const float b_o = b_ih[3*HID + col] + b_hh[3*HID + col];

  // cell state, hidden-dropout mask, initial h -> registers + stage s_h
  float mh_[4], c_[4], h_[4];
  #pragma unroll
  for (int e = 0; e < 4; ++e) {
    const int grow = row_base + rb4 + e;
    mh_[e] = mask_h[grow * HID + col];
    c_[e]  = c0[grow * HID + col];
    h_[e]  = h0[grow * HID + col];
    const int lrow = rb4 + e;
    const int off  = (lrow * 512 + col * 2) ^ ((lrow & 7) << 4);
    *(__bf16*)((char*)s_h + off) = (__bf16)(h_[e] * mh_[e]);
  }

  // x staging slice: wave r stages row r; lane covers 4 consecutive k
  const int xrow = r;
  const int xk   = lane * 4;
  const floatx4 mx_ = *(const floatx4*)(mask_x + (row_base + xrow) * DIM + xk);
  const int xoff = (xrow * 512 + xk * 2) ^ ((xrow & 7) << 4);

  __syncthreads();   // s_bs + s_h ready

  // stage x(0)  (t<256 always fully active: min length = T/2)
  {
    floatx4 xv = *(const floatx4*)(x + (size_t)(row_base + xrow) * DIM + xk);
    floatx4 xm = xv * mx_;
    bf16x4 xb; xb[0]=(__bf16)xm[0]; xb[1]=(__bf16)xm[1]; xb[2]=(__bf16)xm[2]; xb[3]=(__bf16)xm[3];
    *(bf16x4*)((char*)s_x + xoff) = xb;
  }
  __syncthreads();

  const int arow  = l15;                     // A-frag row
  const int abase = arow * 512 + l4 * 16;    // + m*64 bytes per K-step
  const int aswz  = (arow & 7) << 4;

  float* outp = out + (size_t)(row_base + rb4) * HID + col;

  for (int t = 0; t < T_STEPS; ++t) {
    const int bsz = s_bs[t];
    if (bsz > row_base) {
      // prefetch x(t+1) into regs (hides HBM under MFMA)
      floatx4 xn;
      const bool pf = (t + 1 < T_STEPS) && (s_bs[t + 1] > row_base);
      if (pf) xn = *(const floatx4*)(x + ((size_t)(t + 1) * BATCH + row_base + xrow) * DIM + xk);

      // ---- gates = (x·mx)@Wih^T + (h·mh)@Whh^T for 4 gate tiles, in-register ----
      floatx4 a0, a1, a2, a3;
      a0 = a1 = a2 = a3 = (floatx4)(0.0f);
      #pragma unroll
      for (int m = 0; m < 8; ++m) {
        const int ab = (abase + m * 64) ^ aswz;
        bf16x8 ax = *(const bf16x8*)((const char*)s_x + ab);
        bf16x8 ah = *(const bf16x8*)((const char*)s_h + ab);
        a0 = __builtin_amdgcn_mfma_f32_16x16x32_bf16(ax, wih[0][m], a0, 0, 0, 0);
        a1 = __builtin_amdgcn_mfma_f32_16x16x32_bf16(ax, wih[1][m], a1, 0, 0, 0);
        a2 = __builtin_amdgcn_mfma_f32_16x16x32_bf16(ax, wih[2][m], a2, 0, 0, 0);
        a3 = __builtin_amdgcn_mfma_f32_16x16x32_bf16(ax, wih[3][m], a3, 0, 0, 0);
        a0 = __builtin_amdgcn_mfma_f32_16x16x32_bf16(ah, whh[0][m], a0, 0, 0, 0);
        a1 = __builtin_amdgcn_mfma_f32_16x16x32_bf16(ah, whh[1][m], a1, 0, 0, 0);
        a2 = __builtin_amdgcn_mfma_f32_16x16x32_bf16(ah, whh[2][m], a2, 0, 0, 0);
        a3 = __builtin_amdgcn_mfma_f32_16x16x32_bf16(ah, whh[3][m], a3, 0, 0, 0);
      }
      __syncthreads();   // all waves done READING s_x/s_h before overwrite

      // ---- LSTM cell, fully in-register (C layout: col=lane&15, row=rb4+reg) ----
      #pragma unroll
      for (int e = 0; e < 4; ++e) {
        const int lrow = rb4 + e;
        const bool active = (row_base + lrow) < bsz;
        const float iv = sigf(a0[e] + b_i);
        const float fv = sigf(a1[e] + b_f);
        const float gv = tanh_f(a2[e] + b_g);
        const float ov = sigf(a3[e] + b_o);
        const float cc = fv * c_[e] + iv * gv;
        const float hh = ov * tanh_f(cc);
        if (active) {
          c_[e] = cc;
          h_[e] = hh;
          const int off = (lrow * 512 + col * 2) ^ ((lrow & 7) << 4);
          *(__bf16*)((char*)s_h + off) = (__bf16)(hh * mh_[e]);
        }
        outp[(size_t)t * (BATCH * HID) + e * HID] = active ? hh : 0.0f;
      }

      // stage x(t+1)
      if (pf) {
        floatx4 xm = xn * mx_;
        bf16x4 xb; xb[0]=(__bf16)xm[0]; xb[1]=(__bf16)xm[1]; xb[2]=(__bf16)xm[2]; xb[3]=(__bf16)xm[3];
        *(bf16x4*)((char*)s_x + xoff) = xb;
      }
      __syncthreads();   // s_h/s_x ready for next step
    } else {
      // whole row-block inactive: zero output, state frozen
      #pragma unroll
      for (int e = 0; e < 4; ++e)
        outp[(size_t)t * (BATCH * HID) + e * HID] = 0.0f;
    }
  }

  // epilogue
  #pragma unroll
  for (int e = 0; e < 4; ++e) {
    const int grow = row_base + rb4 + e;
    hn_out[grow * HID + col] = h_[e];
    cn_out[grow * HID + col] = c_[e];
  }
}

extern "C" void kernel_launch(void* const* d_in, const int* in_sizes, int n_in,
                              void* d_out, int out_size, void* d_ws, size_t ws_size,
                              hipStream_t stream) {
  const float* x      = (const float*)d_in[0];
  const float* h0     = (const float*)d_in[1];
  const float* c0     = (const float*)d_in[2];
  const float* mask_x = (const float*)d_in[3];
  const float* mask_h = (const float*)d_in[4];
  const float* W_ih   = (const float*)d_in[5];
  const float* W_hh   = (const float*)d_in[6];
  const float* b_ih   = (const float*)d_in[7];
  const float* b_hh   = (const float*)d_in[8];
  const int*   bs     = (const int*)d_in[9];

  float* out = (float*)d_out;
  float* hn  = out + (size_t)T_STEPS * BATCH * HID;
  float* cn  = hn + (size_t)BATCH * HID;

  lstm_wg<<<NG, 1024, 0, stream>>>(x, h0, c0, mask_x, mask_h, W_ih, W_hh,
                                   b_ih, b_hh, bs, out, hn, cn);
}

// Round 3
// 1597.644 us; speedup vs baseline: 7.8763x; 7.8763x over previous
//
#include <hip/hip_runtime.h>
#include <hip/hip_bf16.h>

#define T_STEPS 512
#define BATCH   256
#define DIM     256
#define HID     256

using bf16x8  = __attribute__((ext_vector_type(8))) __bf16;
using floatx4 = __attribute__((ext_vector_type(4))) float;

__device__ __forceinline__ float sigf(float x)   { return 1.0f / (1.0f + __expf(-x)); }
__device__ __forceinline__ float tanh_f(float x) { return 1.0f - 2.0f / (1.0f + __expf(2.0f * x)); }

__device__ __forceinline__ bf16x8 cvt8(const float* p) {
  floatx4 a = *(const floatx4*)p;
  floatx4 b = *(const floatx4*)(p + 4);
  bf16x8 r;
  r[0]=(__bf16)a[0]; r[1]=(__bf16)a[1]; r[2]=(__bf16)a[2]; r[3]=(__bf16)a[3];
  r[4]=(__bf16)b[0]; r[5]=(__bf16)b[1]; r[6]=(__bf16)b[2]; r[7]=(__bf16)b[3];
  return r;
}

// stage 16 masked f32 -> bf16 into swizzled LDS row
__device__ __forceinline__ void stage16(__bf16* sbuf, int srow, int cb, const float* v) {
  bf16x8 lo, hi;
  #pragma unroll
  for (int e = 0; e < 8; ++e) { lo[e] = (__bf16)v[e]; hi[e] = (__bf16)v[8 + e]; }
  const int base = srow * 512 + cb * 2;
  const int swz  = (srow & 7) << 4;
  *(bf16x8*)((char*)sbuf + (base ^ swz))        = lo;
  *(bf16x8*)((char*)sbuf + ((base + 16) ^ swz)) = hi;
}

__global__ void init_ws(int* __restrict__ bar) { bar[threadIdx.x] = 0; }

// 128 WGs x 256 thr: group g (16 rows) x col-WG s (32 h-cols).
// Weights: 128 VGPR/lane (resident). h exchange: L3 mailbox, relaxed
// agent atomics only (no fences), parity double-buffered, flag epochs.
__global__ __launch_bounds__(256, 1) void lstm_s8(
    const float* __restrict__ x, const float* __restrict__ h0,
    const float* __restrict__ c0,
    const float* __restrict__ mask_x, const float* __restrict__ mask_h,
    const float* __restrict__ W_ih, const float* __restrict__ W_hh,
    const float* __restrict__ b_ih, const float* __restrict__ b_hh,
    const int* __restrict__ bs_g,
    float* __restrict__ out, float* __restrict__ hn_out, float* __restrict__ cn_out,
    int* __restrict__ flg, float* __restrict__ mb) {

  const int tid = threadIdx.x;
  const int g   = blockIdx.x & 15;   // row group; members {g+16k} share an XCD under round-robin
  const int s   = blockIdx.x >> 4;   // col-WG 0..7
  const int row_base = g * 16;
  const int lane = tid & 63;
  const int w    = tid >> 6;         // wave id == gate id (i,f,g,o)
  const int l15  = lane & 15;
  const int l4   = lane >> 4;

  // cell mapping: thread -> (row, 2 cols)
  const int crow  = tid >> 4;
  const int cv    = tid & 15;
  const int gcol0 = s * 32 + cv;
  const int gcol1 = gcol0 + 16;

  // staging mapping: thread -> (row, 16 cols)
  const int srow = tid & 15;
  const int cb   = (tid >> 4) * 16;

  __shared__ alignas(16) __bf16 s_x[16 * 256];      // 8 KB swizzled
  __shared__ alignas(16) __bf16 s_h[16 * 256];      // 8 KB swizzled
  __shared__ alignas(16) float  s_gates[16 * 128];  // 8 KB
  __shared__ int s_bs[T_STEPS];

  for (int i = tid; i < T_STEPS; i += 256) s_bs[i] = bs_g[i];

  // ---- stationary weights (gate w, h-cols s*32 + T*16 + l15): 128 VGPR ----
  bf16x8 wih[2][8], whh[2][8];
  #pragma unroll
  for (int Tt = 0; Tt < 2; ++Tt) {
    const size_t wr = (size_t)(w * 256 + s * 32 + Tt * 16 + l15) * 256;
    #pragma unroll
    for (int m = 0; m < 8; ++m) {
      wih[Tt][m] = cvt8(W_ih + wr + m * 32 + l4 * 8);
      whh[Tt][m] = cvt8(W_hh + wr + m * 32 + l4 * 8);
    }
  }

  // masks for staging slice
  floatx4 mxs[4], mhs[4];
  #pragma unroll
  for (int jj = 0; jj < 4; ++jj) {
    mxs[jj] = *(const floatx4*)(mask_x + (row_base + srow) * DIM + cb + jj * 4);
    mhs[jj] = *(const floatx4*)(mask_h + (row_base + srow) * HID + cb + jj * 4);
  }

  // biases for cell cols
  float bb[4][2];
  #pragma unroll
  for (int q = 0; q < 4; ++q) {
    bb[q][0] = b_ih[q * 256 + gcol0] + b_hh[q * 256 + gcol0];
    bb[q][1] = b_ih[q * 256 + gcol1] + b_hh[q * 256 + gcol1];
  }

  float c_[2], h_[2];
  c_[0] = c0[(row_base + crow) * HID + gcol0];
  c_[1] = c0[(row_base + crow) * HID + gcol1];
  h_[0] = h0[(row_base + crow) * HID + gcol0];
  h_[1] = h0[(row_base + crow) * HID + gcol1];

  // stage s_h(0) and s_x(0)
  {
    float v[16];
    #pragma unroll
    for (int jj = 0; jj < 4; ++jj) {
      floatx4 hv = *(const floatx4*)(h0 + (row_base + srow) * HID + cb + jj * 4);
      v[jj*4+0] = hv[0] * mhs[jj][0]; v[jj*4+1] = hv[1] * mhs[jj][1];
      v[jj*4+2] = hv[2] * mhs[jj][2]; v[jj*4+3] = hv[3] * mhs[jj][3];
    }
    stage16(s_h, srow, cb, v);
    #pragma unroll
    for (int jj = 0; jj < 4; ++jj) {
      floatx4 xv = *(const floatx4*)(x + (size_t)(row_base + srow) * DIM + cb + jj * 4);
      v[jj*4+0] = xv[0] * mxs[jj][0]; v[jj*4+1] = xv[1] * mxs[jj][1];
      v[jj*4+2] = xv[2] * mxs[jj][2]; v[jj*4+3] = xv[3] * mxs[jj][3];
    }
    stage16(s_x, srow, cb, v);
  }
  __syncthreads();

  const int aswz = (l15 & 7) << 4;
  const int ab0  = l15 * 512 + l4 * 16;

  for (int t = 0; t < T_STEPS; ++t) {
    const int bszt = s_bs[t];
    if (bszt <= row_base) {
      // group inactive forever (bs non-increasing): zero out, no barriers
      float* op = out + (size_t)t * (BATCH * HID) + (row_base + crow) * HID;
      op[gcol0] = 0.0f; op[gcol1] = 0.0f;
      continue;
    }
    const bool act_n = (t + 1 < T_STEPS) && (s_bs[t + 1] > row_base);

    // prefetch x(t+1)
    floatx4 xpf[4];
    if (act_n) {
      const float* xp = x + ((size_t)(t + 1) * BATCH + row_base + srow) * DIM + cb;
      #pragma unroll
      for (int jj = 0; jj < 4; ++jj) xpf[jj] = *(const floatx4*)(xp + jj * 4);
    }

    // ---- MFMA: gate w, 2 tiles, K=256, x-mat + h-mat into same acc ----
    floatx4 acc0, acc1;
    acc0 = acc1 = (floatx4)(0.0f);
    #pragma unroll
    for (int m = 0; m < 8; ++m) {
      const int ab = (ab0 + m * 64) ^ aswz;
      bf16x8 ax = *(const bf16x8*)((const char*)s_x + ab);
      bf16x8 ah = *(const bf16x8*)((const char*)s_h + ab);
      acc0 = __builtin_amdgcn_mfma_f32_16x16x32_bf16(ax, wih[0][m], acc0, 0, 0, 0);
      acc0 = __builtin_amdgcn_mfma_f32_16x16x32_bf16(ah, whh[0][m], acc0, 0, 0, 0);
      acc1 = __builtin_amdgcn_mfma_f32_16x16x32_bf16(ax, wih[1][m], acc1, 0, 0, 0);
      acc1 = __builtin_amdgcn_mfma_f32_16x16x32_bf16(ah, whh[1][m], acc1, 0, 0, 0);
    }
    // C layout: col = l15, row = l4*4 + e
    #pragma unroll
    for (int e = 0; e < 4; ++e) {
      s_gates[(l4 * 4 + e) * 128 + w * 32 + l15]      = acc0[e];
      s_gates[(l4 * 4 + e) * 128 + w * 32 + 16 + l15] = acc1[e];
    }
    __syncthreads();

    // ---- cell (fp32, in-register state) ----
    {
      const bool ract = (row_base + crow) < bszt;
      float o0, o1;
      #pragma unroll
      for (int k = 0; k < 2; ++k) {
        const int cc2 = cv + k * 16;
        const float gi = s_gates[crow * 128 + 0 * 32 + cc2];
        const float gf = s_gates[crow * 128 + 1 * 32 + cc2];
        const float gg = s_gates[crow * 128 + 2 * 32 + cc2];
        const float go = s_gates[crow * 128 + 3 * 32 + cc2];
        const float iv = sigf(gi + bb[0][k]);
        const float fv = sigf(gf + bb[1][k]);
        const float gv = tanh_f(gg + bb[2][k]);
        const float ov = sigf(go + bb[3][k]);
        const float cc = fv * c_[k] + iv * gv;
        const float hh = ov * tanh_f(cc);
        if (ract) { c_[k] = cc; h_[k] = hh; }
        (k ? o1 : o0) = ract ? hh : 0.0f;
      }
      float* op = out + (size_t)t * (BATCH * HID) + (row_base + crow) * HID;
      op[gcol0] = o0; op[gcol1] = o1;
      if (act_n) {
        float* mbw = mb + ((t + 1) & 1) * (BATCH * HID) + (row_base + crow) * HID;
        __hip_atomic_store(mbw + gcol0, h_[0], __ATOMIC_RELAXED, __HIP_MEMORY_SCOPE_AGENT);
        __hip_atomic_store(mbw + gcol1, h_[1], __ATOMIC_RELAXED, __HIP_MEMORY_SCOPE_AGENT);
      }
    }

    if (act_n) {
      // stage s_x(t+1) (A-reads finished before the post-gates barrier)
      {
        float v[16];
        #pragma unroll
        for (int jj = 0; jj < 4; ++jj) {
          v[jj*4+0] = xpf[jj][0] * mxs[jj][0]; v[jj*4+1] = xpf[jj][1] * mxs[jj][1];
          v[jj*4+2] = xpf[jj][2] * mxs[jj][2]; v[jj*4+3] = xpf[jj][3] * mxs[jj][3];
        }
        stage16(s_x, srow, cb, v);
      }
      // ---- fence-free epoch barrier across the 8 col-WGs ----
      asm volatile("s_waitcnt vmcnt(0)" ::: "memory");   // mailbox stores ack'd at LLC
      __syncthreads();                                    // all threads' stores done
      const int target = t + 1;
      if (tid == 0)
        __hip_atomic_store(flg + g * 8 + s, target, __ATOMIC_RELAXED, __HIP_MEMORY_SCOPE_AGENT);
      int fv_;
      do {
        fv_ = __hip_atomic_load(flg + g * 8 + (lane & 7), __ATOMIC_RELAXED, __HIP_MEMORY_SCOPE_AGENT);
      } while (!__all(fv_ >= target));
      asm volatile("" ::: "memory");

      // ---- stage s_h(t+1) from mailbox ----
      {
        const float* mbr = mb + ((t + 1) & 1) * (BATCH * HID) + (row_base + srow) * HID + cb;
        float v[16];
        #pragma unroll
        for (int j = 0; j < 8; ++j) {
          union { unsigned long long u; float f[2]; } uu;
          uu.u = __hip_atomic_load((const unsigned long long*)(mbr + j * 2),
                                   __ATOMIC_RELAXED, __HIP_MEMORY_SCOPE_AGENT);
          v[j * 2]     = uu.f[0];
          v[j * 2 + 1] = uu.f[1];
        }
        #pragma unroll
        for (int jj = 0; jj < 4; ++jj) {
          v[jj*4+0] *= mhs[jj][0]; v[jj*4+1] *= mhs[jj][1];
          v[jj*4+2] *= mhs[jj][2]; v[jj*4+3] *= mhs[jj][3];
        }
        stage16(s_h, srow, cb, v);
      }
      __syncthreads();
    }
  }

  // epilogue
  hn_out[(row_base + crow) * HID + gcol0] = h_[0];
  hn_out[(row_base + crow) * HID + gcol1] = h_[1];
  cn_out[(row_base + crow) * HID + gcol0] = c_[0];
  cn_out[(row_base + crow) * HID + gcol1] = c_[1];
}

extern "C" void kernel_launch(void* const* d_in, const int* in_sizes, int n_in,
                              void* d_out, int out_size, void* d_ws, size_t ws_size,
                              hipStream_t stream) {
  const float* x      = (const float*)d_in[0];
  const float* h0     = (const float*)d_in[1];
  const float* c0     = (const float*)d_in[2];
  const float* mask_x = (const float*)d_in[3];
  const float* mask_h = (const float*)d_in[4];
  const float* W_ih   = (const float*)d_in[5];
  const float* W_hh   = (const float*)d_in[6];
  const float* b_ih   = (const float*)d_in[7];
  const float* b_hh   = (const float*)d_in[8];
  const int*   bs     = (const int*)d_in[9];

  float* out = (float*)d_out;
  float* hn  = out + (size_t)T_STEPS * BATCH * HID;
  float* cn  = hn + (size_t)BATCH * HID;

  int*   flg = (int*)d_ws;                       // 256 ints (zeroed every launch)
  float* mb  = (float*)((char*)d_ws + 1024);     // 2 x B x H f32 mailbox (512 KB)

  init_ws<<<1, 256, 0, stream>>>(flg);
  lstm_s8<<<128, 256, 0, stream>>>(x, h0, c0, mask_x, mask_h, W_ih, W_hh,
                                   b_ih, b_hh, bs, out, hn, cn, flg, mb);
}